// Round 1
// baseline (472.717 us; speedup 1.0000x reference)
//
#include <hip/hip_runtime.h>
#include <hip/hip_bf16.h>
#include <cstdint>

typedef __bf16 bf16x8 __attribute__((ext_vector_type(8)));
typedef __bf16 bf16x4 __attribute__((ext_vector_type(4)));
typedef float  f32x4  __attribute__((ext_vector_type(4)));

__device__ __forceinline__ f32x4 mfma16(bf16x8 a, bf16x8 b, f32x4 c) {
  return __builtin_amdgcn_mfma_f32_16x16x32_bf16(a, b, c, 0, 0, 0);
}

__device__ __forceinline__ void gload_lds16(const __bf16* g, __bf16* l) {
  __builtin_amdgcn_global_load_lds(
      (const __attribute__((address_space(1))) void*)g,
      (__attribute__((address_space(3))) void*)l, 16, 0, 0);
}

// ---------------- fp32 -> bf16 convert (x4 per thread) ----------------
__global__ __launch_bounds__(256) void cvt_bf16_kernel(const float* __restrict__ in,
                                                       __bf16* __restrict__ out, int n4) {
  int i = blockIdx.x * 256 + threadIdx.x;
  if (i < n4) {
    float4 v = ((const float4*)in)[i];
    bf16x4 o;
    o[0] = (__bf16)v.x; o[1] = (__bf16)v.y; o[2] = (__bf16)v.z; o[3] = (__bf16)v.w;
    ((bf16x4*)out)[i] = o;
  }
}

// ------------- transpose + cvt: src (R x C) f32 -> dst (C x R) bf16 -------------
__global__ __launch_bounds__(256) void transpose_cvt_kernel(const float* __restrict__ src,
                                                            __bf16* __restrict__ dst,
                                                            int R, int C) {
  __shared__ float tile[32][33];
  int r0 = blockIdx.y * 32, c0 = blockIdx.x * 32;
  int tx = threadIdx.x & 31, ty = threadIdx.x >> 5;
#pragma unroll
  for (int i = 0; i < 4; ++i)
    tile[ty + i * 8][tx] = src[(size_t)(r0 + ty + i * 8) * C + c0 + tx];
  __syncthreads();
#pragma unroll
  for (int i = 0; i < 4; ++i) {
    int rr = ty + i * 8;
    dst[(size_t)(c0 + rr) * R + r0 + tx] = (__bf16)tile[tx][rr];
  }
}

// ------------- bf16 GEMM, A (MxK) row-major, Bt (NxK) row-major = B^T -------------
// 128x128 tile / block, 4 waves each 64x64, BK=32, double-buffered LDS,
// global_load_lds width-16 staging (m97 structure).
// EPI==0: qkv epilogue -> scatter q/k (row-major [bh][n][c]) and vT ([bh][c][n]), +bias.
// EPI==1: proj epilogue -> fp32 out (MxN) + bias.
template <int EPI>
__global__ __launch_bounds__(256) void gemm_bt_kernel(
    const __bf16* __restrict__ A, const __bf16* __restrict__ Bt,
    int M, int N, int K,
    const float* __restrict__ bias,
    float* __restrict__ outF,
    __bf16* __restrict__ qo, __bf16* __restrict__ ko, __bf16* __restrict__ vTo) {
  __shared__ __attribute__((aligned(16))) __bf16 lds[2][2][4096];  // [buf][A/B][128*32]
  const int t = threadIdx.x;
  const int l = t & 63, w = t >> 6;
  const int wm = (w >> 1) * 64, wn = (w & 1) * 64;
  const int m0 = blockIdx.y * 128, n0 = blockIdx.x * 128;
  const int nk = K >> 5;

  auto stage = [&](int buf, int kt) {
    const __bf16* As = A + (size_t)m0 * K + kt * 32;
    const __bf16* Bs = Bt + (size_t)n0 * K + kt * 32;
#pragma unroll
    for (int rnd = 0; rnd < 2; ++rnd) {
      int li = rnd * 256 + t;
      int row = li >> 2, c8 = (li & 3) * 8;
      gload_lds16(As + (size_t)row * K + c8, &lds[buf][0][li * 8]);
      gload_lds16(Bs + (size_t)row * K + c8, &lds[buf][1][li * 8]);
    }
  };

  f32x4 acc[4][4] = {};
  stage(0, 0);
  __syncthreads();
  int buf = 0;
  for (int kt = 0; kt < nk; ++kt) {
    if (kt + 1 < nk) stage(buf ^ 1, kt + 1);
    bf16x8 af[4], bfv[4];
    const __bf16* la = &lds[buf][0][0];
    const __bf16* lb = &lds[buf][1][0];
#pragma unroll
    for (int mt = 0; mt < 4; ++mt)
      af[mt] = *(const bf16x8*)(la + (wm + mt * 16 + (l & 15)) * 32 + (l >> 4) * 8);
#pragma unroll
    for (int nt = 0; nt < 4; ++nt)
      bfv[nt] = *(const bf16x8*)(lb + (wn + nt * 16 + (l & 15)) * 32 + (l >> 4) * 8);
#pragma unroll
    for (int mt = 0; mt < 4; ++mt)
#pragma unroll
      for (int nt = 0; nt < 4; ++nt)
        acc[mt][nt] = mfma16(af[mt], bfv[nt], acc[mt][nt]);
    __syncthreads();
    buf ^= 1;
  }

#pragma unroll
  for (int mt = 0; mt < 4; ++mt) {
#pragma unroll
    for (int nt = 0; nt < 4; ++nt) {
#pragma unroll
      for (int r = 0; r < 4; ++r) {
        int row = m0 + wm + mt * 16 + (l >> 4) * 4 + r;  // C/D: row=(l>>4)*4+reg
        int col = n0 + wn + nt * 16 + (l & 15);          //      col=l&15
        float val = acc[mt][nt][r] + bias[col];
        if constexpr (EPI == 0) {
          int s = col / 768, rem = col - s * 768;
          int h = rem >> 6, c = rem & 63;
          int b = row >> 9, n = row & 511;
          size_t bh = (size_t)(b * 12 + h);
          __bf16 bv = (__bf16)val;
          if (s == 0)      qo[(bh * 512 + n) * 64 + c] = bv;
          else if (s == 1) ko[(bh * 512 + n) * 64 + c] = bv;
          else             vTo[(bh * 64 + c) * 512 + n] = bv;
        } else {
          outF[(size_t)row * N + col] = val;
        }
      }
    }
  }
}

// ------------- fused attention: S=scale*qk^T + decomposed rel bias, exp, PV -------------
// block = one (bh, 64-query tile); 4 waves x 16 queries each; loop over 32-key blocks.
// No max-subtraction: logits bounded (|qk|*scale + bias ~ O(3)) so exp is safe.
__global__ __launch_bounds__(256) void attn_kernel(
    const __bf16* __restrict__ qg, const __bf16* __restrict__ kg,
    const __bf16* __restrict__ vT,
    const float* __restrict__ rpd, const float* __restrict__ rph,
    const float* __restrict__ rpw,
    __bf16* __restrict__ attn_out) {
  const int bh = blockIdx.x >> 3;
  const int qb = blockIdx.x & 7;
  const int t = threadIdx.x, w = t >> 6, l = t & 63;
  __shared__ float bias_lds[64][25];                              // 24 used, pad
  __shared__ __attribute__((aligned(16))) __bf16 p_lds[4][16][32];  // per-wave P tile

  // per-q-row bias components: bd[8] | bh[8] | bw[8], each a 64-length dot q.R
  for (int o = t; o < 64 * 24; o += 256) {
    int row = o / 24, idx = o - row * 24;
    int n = qb * 64 + row;
    const __bf16* qrow = qg + ((size_t)bh * 512 + n) * 64;
    const float* R;
    int d;
    if (idx < 8)       { d = (n >> 6)       - idx        + 7; R = rpd; }
    else if (idx < 16) { d = ((n >> 3) & 7) - (idx - 8)  + 7; R = rph; }
    else               { d = (n & 7)        - (idx - 16) + 7; R = rpw; }
    const float* Rr = R + d * 64;
    float s = 0.f;
#pragma unroll
    for (int c8 = 0; c8 < 8; ++c8) {
      bf16x8 qv = *(const bf16x8*)(qrow + c8 * 8);
      float4 r0 = *(const float4*)(Rr + c8 * 8);
      float4 r1 = *(const float4*)(Rr + c8 * 8 + 4);
      s += (float)qv[0] * r0.x + (float)qv[1] * r0.y + (float)qv[2] * r0.z + (float)qv[3] * r0.w;
      s += (float)qv[4] * r1.x + (float)qv[5] * r1.y + (float)qv[6] * r1.z + (float)qv[7] * r1.w;
    }
    bias_lds[row][idx] = s;
  }
  __syncthreads();

  const int n0 = qb * 64 + w * 16;
  const __bf16* qbase = qg + ((size_t)bh * 512 + n0) * 64;
  bf16x8 qf0 = *(const bf16x8*)(qbase + (l & 15) * 64 + (l >> 4) * 8);
  bf16x8 qf1 = *(const bf16x8*)(qbase + (l & 15) * 64 + 32 + (l >> 4) * 8);

  const __bf16* kb = kg + (size_t)bh * 512 * 64;
  const __bf16* vb = vT + (size_t)bh * 64 * 512;

  f32x4 accO[4] = {};
  float rs[4] = {0.f, 0.f, 0.f, 0.f};
  const float scale = 0.125f;

  for (int kbk = 0; kbk < 16; ++kbk) {
    const int j0 = kbk * 32;
    f32x4 accS[2] = {};
#pragma unroll
    for (int jt = 0; jt < 2; ++jt) {
      const __bf16* krow = kb + (size_t)(j0 + jt * 16 + (l & 15)) * 64 + (l >> 4) * 8;
      bf16x8 kf0 = *(const bf16x8*)(krow);
      bf16x8 kf1 = *(const bf16x8*)(krow + 32);
      accS[jt] = mfma16(qf0, kf0, accS[jt]);
      accS[jt] = mfma16(qf1, kf1, accS[jt]);
    }
#pragma unroll
    for (int jt = 0; jt < 2; ++jt) {
      int j = j0 + jt * 16 + (l & 15);
      int dd = j >> 6, hh = (j >> 3) & 7, ww = j & 7;
#pragma unroll
      for (int r = 0; r < 4; ++r) {
        int row = w * 16 + (l >> 4) * 4 + r;
        float lg = accS[jt][r] * scale + bias_lds[row][dd] + bias_lds[row][8 + hh] +
                   bias_lds[row][16 + ww];
        float p = __expf(lg);
        rs[r] += p;
        p_lds[w][(l >> 4) * 4 + r][jt * 16 + (l & 15)] = (__bf16)p;
      }
    }
    // re-fragment P (wave-internal LDS round-trip; DS ops are in-order per wave)
    bf16x8 pf = *(const bf16x8*)(&p_lds[w][l & 15][(l >> 4) * 8]);
#pragma unroll
    for (int ct = 0; ct < 4; ++ct) {
      bf16x8 vf = *(const bf16x8*)(vb + (size_t)(ct * 16 + (l & 15)) * 512 + j0 + (l >> 4) * 8);
      accO[ct] = mfma16(pf, vf, accO[ct]);
    }
  }

#pragma unroll
  for (int r = 0; r < 4; ++r) {
    float s = rs[r];
    s += __shfl_xor(s, 1);
    s += __shfl_xor(s, 2);
    s += __shfl_xor(s, 4);
    s += __shfl_xor(s, 8);
    rs[r] = 1.f / s;
  }

  const int b_ = bh / 12, h_ = bh - b_ * 12;
#pragma unroll
  for (int ct = 0; ct < 4; ++ct) {
#pragma unroll
    for (int r = 0; r < 4; ++r) {
      int rr = (l >> 4) * 4 + r;
      float v = accO[ct][r] * rs[r];
      attn_out[((size_t)b_ * 512 + qb * 64 + w * 16 + rr) * 768 + h_ * 64 + ct * 16 + (l & 15)] =
          (__bf16)v;
    }
  }
}

extern "C" void kernel_launch(void* const* d_in, const int* in_sizes, int n_in,
                              void* d_out, int out_size, void* d_ws, size_t ws_size,
                              hipStream_t stream) {
  const float* x      = (const float*)d_in[0];
  const float* w_qkv  = (const float*)d_in[1];
  const float* b_qkv  = (const float*)d_in[2];
  const float* w_proj = (const float*)d_in[3];
  const float* b_proj = (const float*)d_in[4];
  const float* rpd    = (const float*)d_in[5];
  const float* rph    = (const float*)d_in[6];
  const float* rpw    = (const float*)d_in[7];
  float* out = (float*)d_out;

  // workspace layout (all offsets 256B-aligned); total = 105,381,888 B
  char* base = (char*)d_ws;
  __bf16* xb     = (__bf16*)(base);                                  // 16384x768 bf16; reused as attn_out
  __bf16* wqkvT  = (__bf16*)(base + 25165824);                       // 2304x768
  __bf16* wprojT = (__bf16*)(base + 25165824 + 3538944);             // 768x768
  __bf16* qb     = (__bf16*)(base + 25165824 + 3538944 + 1179648);   // 384x512x64
  __bf16* kb     = qb + (size_t)384 * 512 * 64;
  __bf16* vT     = kb + (size_t)384 * 512 * 64;

  cvt_bf16_kernel<<<12288, 256, 0, stream>>>(x, xb, 12582912 / 4);
  transpose_cvt_kernel<<<dim3(2304 / 32, 768 / 32), 256, 0, stream>>>(w_qkv, wqkvT, 768, 2304);
  transpose_cvt_kernel<<<dim3(768 / 32, 768 / 32), 256, 0, stream>>>(w_proj, wprojT, 768, 768);

  gemm_bt_kernel<0><<<dim3(2304 / 128, 16384 / 128), 256, 0, stream>>>(
      xb, wqkvT, 16384, 2304, 768, b_qkv, nullptr, qb, kb, vT);

  attn_kernel<<<384 * 8, 256, 0, stream>>>(qb, kb, vT, rpd, rph, rpw, xb);

  gemm_bt_kernel<1><<<dim3(768 / 128, 16384 / 128), 256, 0, stream>>>(
      xb, wprojT, 16384, 768, 768, b_proj, out, nullptr, nullptr, nullptr);
}

// Round 2
// 353.504 us; speedup vs baseline: 1.3372x; 1.3372x over previous
//
#include <hip/hip_runtime.h>
#include <hip/hip_bf16.h>
#include <cstdint>

typedef __bf16 bf16x8 __attribute__((ext_vector_type(8)));
typedef __bf16 bf16x4 __attribute__((ext_vector_type(4)));
typedef float  f32x4  __attribute__((ext_vector_type(4)));

__device__ __forceinline__ f32x4 mfma16(bf16x8 a, bf16x8 b, f32x4 c) {
  return __builtin_amdgcn_mfma_f32_16x16x32_bf16(a, b, c, 0, 0, 0);
}

__device__ __forceinline__ void gload_lds16(const __bf16* g, __bf16* l) {
  __builtin_amdgcn_global_load_lds(
      (const __attribute__((address_space(1))) void*)g,
      (__attribute__((address_space(3))) void*)l, 16, 0, 0);
}

// ---------------- fp32 -> bf16 convert (x4 per thread) ----------------
__global__ __launch_bounds__(256) void cvt_bf16_kernel(const float* __restrict__ in,
                                                       __bf16* __restrict__ out, int n4) {
  int i = blockIdx.x * 256 + threadIdx.x;
  if (i < n4) {
    float4 v = ((const float4*)in)[i];
    bf16x4 o;
    o[0] = (__bf16)v.x; o[1] = (__bf16)v.y; o[2] = (__bf16)v.z; o[3] = (__bf16)v.w;
    ((bf16x4*)out)[i] = o;
  }
}

// ------------- transpose + cvt: src (R x C) f32 -> dst (C x R) bf16 -------------
__global__ __launch_bounds__(256) void transpose_cvt_kernel(const float* __restrict__ src,
                                                            __bf16* __restrict__ dst,
                                                            int R, int C) {
  __shared__ float tile[32][33];
  int r0 = blockIdx.y * 32, c0 = blockIdx.x * 32;
  int tx = threadIdx.x & 31, ty = threadIdx.x >> 5;
#pragma unroll
  for (int i = 0; i < 4; ++i)
    tile[ty + i * 8][tx] = src[(size_t)(r0 + ty + i * 8) * C + c0 + tx];
  __syncthreads();
#pragma unroll
  for (int i = 0; i < 4; ++i) {
    int rr = ty + i * 8;
    dst[(size_t)(c0 + rr) * R + r0 + tx] = (__bf16)tile[tx][rr];
  }
}

// ------------- bf16 GEMM, A (MxK) row-major, Bt (NxK) row-major = B^T -------------
template <int EPI>
__global__ __launch_bounds__(256) void gemm_bt_kernel(
    const __bf16* __restrict__ A, const __bf16* __restrict__ Bt,
    int M, int N, int K,
    const float* __restrict__ bias,
    float* __restrict__ outF,
    __bf16* __restrict__ qo, __bf16* __restrict__ ko, __bf16* __restrict__ vTo) {
  __shared__ __attribute__((aligned(16))) __bf16 lds[2][2][4096];  // [buf][A/B][128*32]
  const int t = threadIdx.x;
  const int l = t & 63, w = t >> 6;
  const int wm = (w >> 1) * 64, wn = (w & 1) * 64;
  const int m0 = blockIdx.y * 128, n0 = blockIdx.x * 128;
  const int nk = K >> 5;

  auto stage = [&](int buf, int kt) {
    const __bf16* As = A + (size_t)m0 * K + kt * 32;
    const __bf16* Bs = Bt + (size_t)n0 * K + kt * 32;
#pragma unroll
    for (int rnd = 0; rnd < 2; ++rnd) {
      int li = rnd * 256 + t;
      int row = li >> 2, c8 = (li & 3) * 8;
      gload_lds16(As + (size_t)row * K + c8, &lds[buf][0][li * 8]);
      gload_lds16(Bs + (size_t)row * K + c8, &lds[buf][1][li * 8]);
    }
  };

  f32x4 acc[4][4] = {};
  stage(0, 0);
  __syncthreads();
  int buf = 0;
  for (int kt = 0; kt < nk; ++kt) {
    if (kt + 1 < nk) stage(buf ^ 1, kt + 1);
    bf16x8 af[4], bfv[4];
    const __bf16* la = &lds[buf][0][0];
    const __bf16* lb = &lds[buf][1][0];
#pragma unroll
    for (int mt = 0; mt < 4; ++mt)
      af[mt] = *(const bf16x8*)(la + (wm + mt * 16 + (l & 15)) * 32 + (l >> 4) * 8);
#pragma unroll
    for (int nt = 0; nt < 4; ++nt)
      bfv[nt] = *(const bf16x8*)(lb + (wn + nt * 16 + (l & 15)) * 32 + (l >> 4) * 8);
#pragma unroll
    for (int mt = 0; mt < 4; ++mt)
#pragma unroll
      for (int nt = 0; nt < 4; ++nt)
        acc[mt][nt] = mfma16(af[mt], bfv[nt], acc[mt][nt]);
    __syncthreads();
    buf ^= 1;
  }

#pragma unroll
  for (int mt = 0; mt < 4; ++mt) {
#pragma unroll
    for (int nt = 0; nt < 4; ++nt) {
#pragma unroll
      for (int r = 0; r < 4; ++r) {
        int row = m0 + wm + mt * 16 + (l >> 4) * 4 + r;
        int col = n0 + wn + nt * 16 + (l & 15);
        float val = acc[mt][nt][r] + bias[col];
        if constexpr (EPI == 0) {
          int s = col / 768, rem = col - s * 768;
          int h = rem >> 6, c = rem & 63;
          int b = row >> 9, n = row & 511;
          size_t bh = (size_t)(b * 12 + h);
          __bf16 bv = (__bf16)val;
          if (s == 0)      qo[(bh * 512 + n) * 64 + c] = bv;
          else if (s == 1) ko[(bh * 512 + n) * 64 + c] = bv;
          else             vTo[(bh * 64 + c) * 512 + n] = bv;
        } else {
          outF[(size_t)row * N + col] = val;
        }
      }
    }
  }
}

// ------------- fused attention, LDS-staged K/V (64-key tiles), dbuf + swizzle -------------
// block = one (bh, 64-query tile); 4 waves x 16 queries each.
// LDS tiles are [row][chunk] with chunk-XOR swizzle: phys_chunk = chunk ^ (row&7),
// 16B chunks. global_load_lds writes LINEAR phys; source address carries the inverse
// (same XOR) permutation; ds_read applies the XOR. (rule #21: both-sides-or-neither)
__device__ __forceinline__ const bf16x8* lds_frag(const __bf16* base, int row, int ch) {
  return (const bf16x8*)(base + row * 64 + ((ch ^ (row & 7)) * 8));
}

__global__ __launch_bounds__(256) void attn_kernel(
    const __bf16* __restrict__ qg, const __bf16* __restrict__ kg,
    const __bf16* __restrict__ vT,
    const float* __restrict__ rpd, const float* __restrict__ rph,
    const float* __restrict__ rpw,
    __bf16* __restrict__ attn_out) {
  // XCD swizzle: 3072 blocks, 8 XCDs -> same-bh blocks co-located per XCD
  const int bid = (blockIdx.x & 7) * 384 + (blockIdx.x >> 3);
  const int bh = bid >> 3;
  const int qb = bid & 7;
  const int t = threadIdx.x, w = t >> 6, l = t & 63;

  __shared__ float bias_lds[64][25];
  __shared__ __attribute__((aligned(16))) __bf16 k_lds[2][64 * 64];
  __shared__ __attribute__((aligned(16))) __bf16 v_lds[2][64 * 64];
  __shared__ __attribute__((aligned(16))) __bf16 p_lds[4][16 * 64];

  // per-q-row bias components: bd[8] | bh[8] | bw[8]; each a 64-length dot q.R
  for (int o = t; o < 64 * 24; o += 256) {
    int row = o / 24, idx = o - row * 24;
    int n = qb * 64 + row;
    const __bf16* qrow = qg + ((size_t)bh * 512 + n) * 64;
    const float* R;
    int d;
    if (idx < 8)       { d = (n >> 6)       - idx        + 7; R = rpd; }
    else if (idx < 16) { d = ((n >> 3) & 7) - (idx - 8)  + 7; R = rph; }
    else               { d = (n & 7)        - (idx - 16) + 7; R = rpw; }
    const float* Rr = R + d * 64;
    float s = 0.f;
#pragma unroll
    for (int c8 = 0; c8 < 8; ++c8) {
      bf16x8 qv = *(const bf16x8*)(qrow + c8 * 8);
      float4 r0 = *(const float4*)(Rr + c8 * 8);
      float4 r1 = *(const float4*)(Rr + c8 * 8 + 4);
      s += (float)qv[0] * r0.x + (float)qv[1] * r0.y + (float)qv[2] * r0.z + (float)qv[3] * r0.w;
      s += (float)qv[4] * r1.x + (float)qv[5] * r1.y + (float)qv[6] * r1.z + (float)qv[7] * r1.w;
    }
    bias_lds[row][idx] = s;
  }

  const int n0 = qb * 64 + w * 16;
  const __bf16* qbase = qg + ((size_t)bh * 512 + n0) * 64;
  bf16x8 qf0 = *(const bf16x8*)(qbase + (l & 15) * 64 + (l >> 4) * 8);
  bf16x8 qf1 = *(const bf16x8*)(qbase + (l & 15) * 64 + 32 + (l >> 4) * 8);

  const __bf16* kb = kg + (size_t)bh * 512 * 64;
  const __bf16* vb = vT + (size_t)bh * 64 * 512;

  auto stage = [&](int sbuf, int j0) {
#pragma unroll
    for (int rnd = 0; rnd < 2; ++rnd) {
      int li = rnd * 256 + t;
      int row = li >> 3, pc = li & 7;
      int lc = pc ^ (row & 7);  // inverse-swizzled source chunk
      gload_lds16(kb + (size_t)(j0 + row) * 64 + lc * 8, &k_lds[sbuf][li * 8]);
    }
#pragma unroll
    for (int rnd = 0; rnd < 2; ++rnd) {
      int li = rnd * 256 + t;
      int row = li >> 3, pc = li & 7;
      int lc = pc ^ (row & 7);
      gload_lds16(vb + (size_t)row * 512 + j0 + lc * 8, &v_lds[sbuf][li * 8]);
    }
  };

  stage(0, 0);
  __syncthreads();  // bias_lds ready + stage(0) drained (implicit vmcnt(0))

  // hoist kbk-independent bias terms: key = jt*16+(l&15): hh=(jt*2+((l&15)>>3))&7, ww=l&7
  float hw_r[4][4];
  const int hb = (l & 15) >> 3;
#pragma unroll
  for (int r = 0; r < 4; ++r) {
    int row = w * 16 + (l >> 4) * 4 + r;
    float bwv = bias_lds[row][16 + (l & 7)];
#pragma unroll
    for (int jt = 0; jt < 4; ++jt)
      hw_r[r][jt] = bias_lds[row][8 + ((jt * 2 + hb) & 7)] + bwv;
  }

  f32x4 accO[4] = {};
  float rs[4] = {0.f, 0.f, 0.f, 0.f};
  const float scale = 0.125f;
  int buf = 0;

  for (int kbk = 0; kbk < 8; ++kbk) {
    if (kbk + 1 < 8) stage(buf ^ 1, (kbk + 1) * 64);
    const __bf16* kl = k_lds[buf];
    const __bf16* vl = v_lds[buf];

    // QK^T: 64 keys, k-dim 64 in two slices
    f32x4 accS[4] = {};
#pragma unroll
    for (int jt = 0; jt < 4; ++jt) {
      int kr = jt * 16 + (l & 15);
      accS[jt] = mfma16(qf0, *lds_frag(kl, kr, (l >> 4)), accS[jt]);
      accS[jt] = mfma16(qf1, *lds_frag(kl, kr, 4 + (l >> 4)), accS[jt]);
    }

    // bias + exp + P write (swizzled scalar writes)
    float bd_r[4];
#pragma unroll
    for (int r = 0; r < 4; ++r) bd_r[r] = bias_lds[w * 16 + (l >> 4) * 4 + r][kbk];
#pragma unroll
    for (int jt = 0; jt < 4; ++jt) {
#pragma unroll
      for (int r = 0; r < 4; ++r) {
        float lg = accS[jt][r] * scale + bd_r[r] + hw_r[r][jt];
        float p = __expf(lg);
        rs[r] += p;
        int q = (l >> 4) * 4 + r;
        int key = jt * 16 + (l & 15);
        p_lds[w][q * 64 + (((key >> 3) ^ (q & 7)) * 8) + (key & 7)] = (__bf16)p;
      }
    }

    // PV: wave-internal LDS round-trip (DS in-order per wave), 2 key-slices of 32
    bf16x8 pf0 = *lds_frag(p_lds[w], l & 15, (l >> 4));
    bf16x8 pf1 = *lds_frag(p_lds[w], l & 15, 4 + (l >> 4));
#pragma unroll
    for (int ct = 0; ct < 4; ++ct) {
      int vr = ct * 16 + (l & 15);
      accO[ct] = mfma16(pf0, *lds_frag(vl, vr, (l >> 4)), accO[ct]);
      accO[ct] = mfma16(pf1, *lds_frag(vl, vr, 4 + (l >> 4)), accO[ct]);
    }
    __syncthreads();  // waves done with buf; staged buf^1 drained
    buf ^= 1;
  }

#pragma unroll
  for (int r = 0; r < 4; ++r) {
    float s = rs[r];
    s += __shfl_xor(s, 1);
    s += __shfl_xor(s, 2);
    s += __shfl_xor(s, 4);
    s += __shfl_xor(s, 8);
    rs[r] = 1.f / s;
  }

  const int b_ = bh / 12, h_ = bh - b_ * 12;
#pragma unroll
  for (int ct = 0; ct < 4; ++ct) {
#pragma unroll
    for (int r = 0; r < 4; ++r) {
      int rr = (l >> 4) * 4 + r;
      float v = accO[ct][r] * rs[r];
      attn_out[((size_t)b_ * 512 + qb * 64 + w * 16 + rr) * 768 + h_ * 64 + ct * 16 + (l & 15)] =
          (__bf16)v;
    }
  }
}

extern "C" void kernel_launch(void* const* d_in, const int* in_sizes, int n_in,
                              void* d_out, int out_size, void* d_ws, size_t ws_size,
                              hipStream_t stream) {
  const float* x      = (const float*)d_in[0];
  const float* w_qkv  = (const float*)d_in[1];
  const float* b_qkv  = (const float*)d_in[2];
  const float* w_proj = (const float*)d_in[3];
  const float* b_proj = (const float*)d_in[4];
  const float* rpd    = (const float*)d_in[5];
  const float* rph    = (const float*)d_in[6];
  const float* rpw    = (const float*)d_in[7];
  float* out = (float*)d_out;

  char* base = (char*)d_ws;
  __bf16* xb     = (__bf16*)(base);                                  // 16384x768 bf16; reused as attn_out
  __bf16* wqkvT  = (__bf16*)(base + 25165824);                       // 2304x768
  __bf16* wprojT = (__bf16*)(base + 25165824 + 3538944);             // 768x768
  __bf16* qb     = (__bf16*)(base + 25165824 + 3538944 + 1179648);   // 384x512x64
  __bf16* kb     = qb + (size_t)384 * 512 * 64;
  __bf16* vT     = kb + (size_t)384 * 512 * 64;

  cvt_bf16_kernel<<<12288, 256, 0, stream>>>(x, xb, 12582912 / 4);
  transpose_cvt_kernel<<<dim3(2304 / 32, 768 / 32), 256, 0, stream>>>(w_qkv, wqkvT, 768, 2304);
  transpose_cvt_kernel<<<dim3(768 / 32, 768 / 32), 256, 0, stream>>>(w_proj, wprojT, 768, 768);

  gemm_bt_kernel<0><<<dim3(2304 / 128, 16384 / 128), 256, 0, stream>>>(
      xb, wqkvT, 16384, 2304, 768, b_qkv, nullptr, qb, kb, vT);

  attn_kernel<<<384 * 8, 256, 0, stream>>>(qb, kb, vT, rpd, rph, rpw, xb);

  gemm_bt_kernel<1><<<dim3(768 / 128, 16384 / 128), 256, 0, stream>>>(
      xb, wprojT, 16384, 768, 768, b_proj, out, nullptr, nullptr, nullptr);
}

// Round 3
// 325.554 us; speedup vs baseline: 1.4520x; 1.0859x over previous
//
#include <hip/hip_runtime.h>
#include <hip/hip_bf16.h>
#include <cstdint>

typedef __bf16 bf16x8 __attribute__((ext_vector_type(8)));
typedef __bf16 bf16x4 __attribute__((ext_vector_type(4)));
typedef float  f32x4  __attribute__((ext_vector_type(4)));

__device__ __forceinline__ f32x4 mfma16(bf16x8 a, bf16x8 b, f32x4 c) {
  return __builtin_amdgcn_mfma_f32_16x16x32_bf16(a, b, c, 0, 0, 0);
}

__device__ __forceinline__ void gload_lds16(const __bf16* g, __bf16* l) {
  __builtin_amdgcn_global_load_lds(
      (const __attribute__((address_space(1))) void*)g,
      (__attribute__((address_space(3))) void*)l, 16, 0, 0);
}

// ---------------- fp32 -> bf16 convert (x4 per thread) ----------------
__global__ __launch_bounds__(256) void cvt_bf16_kernel(const float* __restrict__ in,
                                                       __bf16* __restrict__ out, int n4) {
  int i = blockIdx.x * 256 + threadIdx.x;
  if (i < n4) {
    float4 v = ((const float4*)in)[i];
    bf16x4 o;
    o[0] = (__bf16)v.x; o[1] = (__bf16)v.y; o[2] = (__bf16)v.z; o[3] = (__bf16)v.w;
    ((bf16x4*)out)[i] = o;
  }
}

// ------------- transpose + cvt: src (R x C) f32 -> dst (C x R) bf16 -------------
__global__ __launch_bounds__(256) void transpose_cvt_kernel(const float* __restrict__ src,
                                                            __bf16* __restrict__ dst,
                                                            int R, int C) {
  __shared__ float tile[32][33];
  int r0 = blockIdx.y * 32, c0 = blockIdx.x * 32;
  int tx = threadIdx.x & 31, ty = threadIdx.x >> 5;
#pragma unroll
  for (int i = 0; i < 4; ++i)
    tile[ty + i * 8][tx] = src[(size_t)(r0 + ty + i * 8) * C + c0 + tx];
  __syncthreads();
#pragma unroll
  for (int i = 0; i < 4; ++i) {
    int rr = ty + i * 8;
    dst[(size_t)(c0 + rr) * R + r0 + tx] = (__bf16)tile[tx][rr];
  }
}

// ------------- bf16 GEMM, A (MxK) row-major, Bt (NxK) row-major = B^T -------------
// 1-D grid with bijective XCD swizzle (grid % 8 == 0).
template <int EPI>
__global__ __launch_bounds__(256) void gemm_bt_kernel(
    const __bf16* __restrict__ A, const __bf16* __restrict__ Bt,
    int M, int N, int K, int nbx,
    const float* __restrict__ bias,
    float* __restrict__ outF,
    __bf16* __restrict__ qo, __bf16* __restrict__ ko, __bf16* __restrict__ vTo) {
  __shared__ __attribute__((aligned(16))) __bf16 lds[2][2][4096];  // [buf][A/B][128*32]
  const int t = threadIdx.x;
  const int l = t & 63, w = t >> 6;
  const int wm = (w >> 1) * 64, wn = (w & 1) * 64;
  const int cpx = gridDim.x >> 3;
  const int wg = (blockIdx.x & 7) * cpx + (blockIdx.x >> 3);
  const int m0 = (wg / nbx) * 128, n0 = (wg % nbx) * 128;
  const int nk = K >> 5;

  auto stage = [&](int buf, int kt) {
    const __bf16* As = A + (size_t)m0 * K + kt * 32;
    const __bf16* Bs = Bt + (size_t)n0 * K + kt * 32;
#pragma unroll
    for (int rnd = 0; rnd < 2; ++rnd) {
      int li = rnd * 256 + t;
      int row = li >> 2, c8 = (li & 3) * 8;
      gload_lds16(As + (size_t)row * K + c8, &lds[buf][0][li * 8]);
      gload_lds16(Bs + (size_t)row * K + c8, &lds[buf][1][li * 8]);
    }
  };

  f32x4 acc[4][4] = {};
  stage(0, 0);
  __syncthreads();
  int buf = 0;
  for (int kt = 0; kt < nk; ++kt) {
    if (kt + 1 < nk) stage(buf ^ 1, kt + 1);
    bf16x8 af[4], bfv[4];
    const __bf16* la = &lds[buf][0][0];
    const __bf16* lb = &lds[buf][1][0];
#pragma unroll
    for (int mt = 0; mt < 4; ++mt)
      af[mt] = *(const bf16x8*)(la + (wm + mt * 16 + (l & 15)) * 32 + (l >> 4) * 8);
#pragma unroll
    for (int nt = 0; nt < 4; ++nt)
      bfv[nt] = *(const bf16x8*)(lb + (wn + nt * 16 + (l & 15)) * 32 + (l >> 4) * 8);
#pragma unroll
    for (int mt = 0; mt < 4; ++mt)
#pragma unroll
      for (int nt = 0; nt < 4; ++nt)
        acc[mt][nt] = mfma16(af[mt], bfv[nt], acc[mt][nt]);
    __syncthreads();
    buf ^= 1;
  }

#pragma unroll
  for (int mt = 0; mt < 4; ++mt) {
#pragma unroll
    for (int nt = 0; nt < 4; ++nt) {
#pragma unroll
      for (int r = 0; r < 4; ++r) {
        int row = m0 + wm + mt * 16 + (l >> 4) * 4 + r;
        int col = n0 + wn + nt * 16 + (l & 15);
        float val = acc[mt][nt][r] + bias[col];
        if constexpr (EPI == 0) {
          int s = col / 768, rem = col - s * 768;
          int h = rem >> 6, c = rem & 63;
          int b = row >> 9, n = row & 511;
          size_t bh = (size_t)(b * 12 + h);
          __bf16 bv = (__bf16)val;
          if (s == 0)      qo[(bh * 512 + n) * 64 + c] = bv;
          else if (s == 1) ko[(bh * 512 + n) * 64 + c] = bv;
          else             vTo[(bh * 64 + c) * 512 + n] = bv;
        } else {
          outF[(size_t)row * N + col] = val;
        }
      }
    }
  }
}

// ------------- fused attention, QBLK=128 (4 waves x 32 q), swapped QK^T -------------
// K/V LDS tiles [row][chunk^(row&7)] XOR-swizzled (linear global_load_lds dest,
// inverse-swizzled global source, XOR on ds_read — rule #21).
// QK^T computed as mfma(K,Q) -> S^T: lane l holds q=l&15(+16*qg), keys 4*(l>>4)+r+16*jt
// -> P packs as bf16x4 (4 consecutive keys) -> ds_write_b64 into stride-72 p_lds.
__device__ __forceinline__ const bf16x8* lds_frag(const __bf16* base, int row, int ch) {
  return (const bf16x8*)(base + row * 64 + ((ch ^ (row & 7)) * 8));
}

__global__ __launch_bounds__(256, 2) void attn_kernel(
    const __bf16* __restrict__ qg_, const __bf16* __restrict__ kg,
    const __bf16* __restrict__ vT,
    const float* __restrict__ rpd, const float* __restrict__ rph,
    const float* __restrict__ rpw,
    __bf16* __restrict__ attn_out) {
  // XCD swizzle: 1536 blocks = 8 x 192
  const int bid = (blockIdx.x & 7) * 192 + (blockIdx.x >> 3);
  const int bh = bid >> 2;
  const int qb = bid & 3;
  const int t = threadIdx.x, w = t >> 6, l = t & 63;
  const int lr = l & 15, lh = l >> 4;

  __shared__ float bias_lds[128][25];
  __shared__ float rs_lds[4][32];
  __shared__ __attribute__((aligned(16))) __bf16 k_lds[2][64 * 64];
  __shared__ __attribute__((aligned(16))) __bf16 v_lds[2][64 * 64];
  __shared__ __attribute__((aligned(16))) __bf16 p_lds[4][32 * 72];

  // per-q-row bias components: bd[8] | bh[8] | bw[8]; each a 64-length dot q.R
  for (int o = t; o < 128 * 24; o += 256) {
    int row = o / 24, idx = o - row * 24;
    int n = qb * 128 + row;
    const __bf16* qrow = qg_ + ((size_t)bh * 512 + n) * 64;
    const float* R;
    int d;
    if (idx < 8)       { d = (n >> 6)       - idx        + 7; R = rpd; }
    else if (idx < 16) { d = ((n >> 3) & 7) - (idx - 8)  + 7; R = rph; }
    else               { d = (n & 7)        - (idx - 16) + 7; R = rpw; }
    const float* Rr = R + d * 64;
    float s = 0.f;
#pragma unroll
    for (int c8 = 0; c8 < 8; ++c8) {
      bf16x8 qv = *(const bf16x8*)(qrow + c8 * 8);
      float4 r0 = *(const float4*)(Rr + c8 * 8);
      float4 r1 = *(const float4*)(Rr + c8 * 8 + 4);
      s += (float)qv[0] * r0.x + (float)qv[1] * r0.y + (float)qv[2] * r0.z + (float)qv[3] * r0.w;
      s += (float)qv[4] * r1.x + (float)qv[5] * r1.y + (float)qv[6] * r1.z + (float)qv[7] * r1.w;
    }
    bias_lds[row][idx] = s;
  }

  // Q fragments (B-operand): 2 q-groups x 2 d-slices
  const __bf16* qbase = qg_ + ((size_t)bh * 512 + qb * 128 + w * 32) * 64;
  bf16x8 qf[2][2];
#pragma unroll
  for (int qg = 0; qg < 2; ++qg)
#pragma unroll
    for (int s = 0; s < 2; ++s)
      qf[qg][s] = *(const bf16x8*)(qbase + (qg * 16 + lr) * 64 + s * 32 + lh * 8);

  const __bf16* kb = kg + (size_t)bh * 512 * 64;
  const __bf16* vb = vT + (size_t)bh * 64 * 512;

  auto stage = [&](int sbuf, int j0) {
#pragma unroll
    for (int rnd = 0; rnd < 2; ++rnd) {
      int li = rnd * 256 + t;
      int row = li >> 3, pc = li & 7;
      int lc = pc ^ (row & 7);
      gload_lds16(kb + (size_t)(j0 + row) * 64 + lc * 8, &k_lds[sbuf][li * 8]);
    }
#pragma unroll
    for (int rnd = 0; rnd < 2; ++rnd) {
      int li = rnd * 256 + t;
      int row = li >> 3, pc = li & 7;
      int lc = pc ^ (row & 7);
      gload_lds16(vb + (size_t)row * 512 + j0 + lc * 8, &v_lds[sbuf][li * 8]);
    }
  };

  stage(0, 0);
  __syncthreads();  // bias_lds ready + stage(0) drained

  // hoist kbk-independent bias terms (per lane: q = qg*16+lr fixed):
  // key_local = 16*jt + 4*lh + r -> kh = (2*jt + (lh>>1)) & 7, kw = 4*(lh&1) + r
  float bh_v[2][4], bw_v[2][4];
#pragma unroll
  for (int qg = 0; qg < 2; ++qg) {
    int row = w * 32 + qg * 16 + lr;
#pragma unroll
    for (int jt = 0; jt < 4; ++jt)
      bh_v[qg][jt] = bias_lds[row][8 + ((2 * jt + (lh >> 1)) & 7)];
#pragma unroll
    for (int r = 0; r < 4; ++r)
      bw_v[qg][r] = bias_lds[row][16 + 4 * (lh & 1) + r];
  }

  f32x4 accO[2][4] = {};
  float rs[2] = {0.f, 0.f};
  const float scale = 0.125f;
  __bf16* pw = &p_lds[w][0];
  int buf = 0;

  for (int kbk = 0; kbk < 8; ++kbk) {
    if (kbk + 1 < 8) stage(buf ^ 1, (kbk + 1) * 64);
    const __bf16* kl = k_lds[buf];
    const __bf16* vl = v_lds[buf];

    // QK^T (swapped): accS[qg][jt] = S^T, rows=keys 16jt+4lh+r, col=q
    f32x4 accS[2][4] = {};
#pragma unroll
    for (int jt = 0; jt < 4; ++jt) {
#pragma unroll
      for (int s = 0; s < 2; ++s) {
        bf16x8 kf = *lds_frag(kl, jt * 16 + lr, s * 4 + lh);
        accS[0][jt] = mfma16(kf, qf[0][s], accS[0][jt]);
        accS[1][jt] = mfma16(kf, qf[1][s], accS[1][jt]);
      }
    }

    float bd0 = bias_lds[w * 32 + lr][kbk];
    float bd1 = bias_lds[w * 32 + 16 + lr][kbk];

    // bias + exp + packed P write (b64, stride-72 rows: 2-way = free)
#pragma unroll
    for (int qg = 0; qg < 2; ++qg) {
      float bd = qg ? bd1 : bd0;
#pragma unroll
      for (int jt = 0; jt < 4; ++jt) {
        bf16x4 pv;
#pragma unroll
        for (int r = 0; r < 4; ++r) {
          float p = __expf(accS[qg][jt][r] * scale + bd + bh_v[qg][jt] + bw_v[qg][r]);
          rs[qg] += p;
          pv[r] = (__bf16)p;
        }
        *(bf16x4*)(pw + (qg * 16 + lr) * 72 + jt * 16 + lh * 4) = pv;
      }
    }

    // P read (A-frag) + PV
    bf16x8 pf[2][2];
#pragma unroll
    for (int qg = 0; qg < 2; ++qg)
#pragma unroll
      for (int ks = 0; ks < 2; ++ks)
        pf[qg][ks] = *(const bf16x8*)(pw + (qg * 16 + lr) * 72 + ks * 32 + lh * 8);
#pragma unroll
    for (int ks = 0; ks < 2; ++ks) {
#pragma unroll
      for (int ct = 0; ct < 4; ++ct) {
        bf16x8 vf = *lds_frag(vl, ct * 16 + lr, ks * 4 + lh);
        accO[0][ct] = mfma16(pf[0][ks], vf, accO[0][ct]);
        accO[1][ct] = mfma16(pf[1][ks], vf, accO[1][ct]);
      }
    }
    __syncthreads();
    buf ^= 1;
  }

  // softmax denominators: reduce over lane bits 4-5 (the 4 key-groups per q)
#pragma unroll
  for (int qg = 0; qg < 2; ++qg) {
    float s = rs[qg];
    s += __shfl_xor(s, 16);
    s += __shfl_xor(s, 32);
    if (l < 16) rs_lds[w][qg * 16 + l] = 1.f / s;
  }

  const int b_ = bh / 12, h_ = bh - b_ * 12;
#pragma unroll
  for (int qg = 0; qg < 2; ++qg) {
#pragma unroll
    for (int r = 0; r < 4; ++r) {
      float inv = rs_lds[w][qg * 16 + lh * 4 + r];
      int n = qb * 128 + w * 32 + qg * 16 + lh * 4 + r;
#pragma unroll
      for (int ct = 0; ct < 4; ++ct) {
        float v = accO[qg][ct][r] * inv;
        attn_out[((size_t)b_ * 512 + n) * 768 + h_ * 64 + ct * 16 + lr] = (__bf16)v;
      }
    }
  }
}

extern "C" void kernel_launch(void* const* d_in, const int* in_sizes, int n_in,
                              void* d_out, int out_size, void* d_ws, size_t ws_size,
                              hipStream_t stream) {
  const float* x      = (const float*)d_in[0];
  const float* w_qkv  = (const float*)d_in[1];
  const float* b_qkv  = (const float*)d_in[2];
  const float* w_proj = (const float*)d_in[3];
  const float* b_proj = (const float*)d_in[4];
  const float* rpd    = (const float*)d_in[5];
  const float* rph    = (const float*)d_in[6];
  const float* rpw    = (const float*)d_in[7];
  float* out = (float*)d_out;

  char* base = (char*)d_ws;
  __bf16* xb     = (__bf16*)(base);                                  // 16384x768 bf16; reused as attn_out
  __bf16* wqkvT  = (__bf16*)(base + 25165824);                       // 2304x768
  __bf16* wprojT = (__bf16*)(base + 25165824 + 3538944);             // 768x768
  __bf16* qb     = (__bf16*)(base + 25165824 + 3538944 + 1179648);   // 384x512x64
  __bf16* kb     = qb + (size_t)384 * 512 * 64;
  __bf16* vT     = kb + (size_t)384 * 512 * 64;

  cvt_bf16_kernel<<<12288, 256, 0, stream>>>(x, xb, 12582912 / 4);
  transpose_cvt_kernel<<<dim3(2304 / 32, 768 / 32), 256, 0, stream>>>(w_qkv, wqkvT, 768, 2304);
  transpose_cvt_kernel<<<dim3(768 / 32, 768 / 32), 256, 0, stream>>>(w_proj, wprojT, 768, 768);

  gemm_bt_kernel<0><<<2304, 256, 0, stream>>>(
      xb, wqkvT, 16384, 2304, 768, 18, b_qkv, nullptr, qb, kb, vT);

  attn_kernel<<<1536, 256, 0, stream>>>(qb, kb, vT, rpd, rph, rpw, xb);

  gemm_bt_kernel<1><<<768, 256, 0, stream>>>(
      xb, wprojT, 16384, 768, 768, 6, b_proj, out, nullptr, nullptr, nullptr);
}